// Round 4
// baseline (70.232 us; speedup 1.0000x reference)
//
#include <hip/hip_runtime.h>

#define NNODE  18
#define ADJ_F  324                     // floats per batch matrix
#define ADJ_B  1296                    // bytes per batch matrix
#define NF_B   72                      // bytes per batch node-features
#define TILE   29                      // batches per buffer
#define GRID   512                     // persistent blocks = 2 per CU
#define ADJ_TILE_B (TILE * ADJ_B)      // 37,584
#define NF_TILE_B  (TILE * NF_B)       // 2,088
#define NF_SEC_B   2096                // padded to 16
#define BUF_B      (ADJ_TILE_B + NF_SEC_B)   // 39,680 ; x2 buffers = 79,360 -> 2 blocks/CU
#define ADJ_CHUNKS 37                  // 36 full 1KiB + 720 B (lane<45)
#define STAGE_OPS  40                  // 37 adj + 3 nf DMA ops per tile (FIXED count)

__device__ __forceinline__ void gload_lds16(const void* g, void* l) {
    __builtin_amdgcn_global_load_lds((const __attribute__((address_space(1))) void*)g,
                                     (__attribute__((address_space(3))) void*)l, 16, 0, 0);
}

__global__ __launch_bounds__(64, 1) void gcnn_fused(
    const float* __restrict__ nf,      // [B,18]
    const float* __restrict__ adj,     // [B,18,18]
    const float* __restrict__ proj_w, const float* __restrict__ proj_b,
    const float* __restrict__ w1, const float* __restrict__ b1,   // [10,18],[10]
    const float* __restrict__ w2, const float* __restrict__ b2,   // [8,10],[8]
    const float* __restrict__ w3, const float* __restrict__ b3,   // [2,8],[2]
    float* __restrict__ out,           // [B,2]
    int B)
{
    extern __shared__ __align__(16) char smem[];   // 2 x BUF_B, LINEAR (global_load_lds)
    const int lane = threadIdx.x;                  // block = 1 wave, no __syncthreads anywhere
    const int NT = (B + TILE - 1) / TILE;          // 4520
    const unsigned adjLim = (unsigned)B * ADJ_B - 16;   // clamp keeps tail-tile DMA in-bounds
    const unsigned nfLim  = (unsigned)B * NF_B  - 16;   // (fixed op count => fixed vmcnt)

    char* bA = smem;
    char* bB = smem + BUF_B;

    auto stage = [&](int t, char* buf) {
        // adj: 37 DMA ops
        unsigned abase = (unsigned)t * ADJ_TILE_B + lane * 16;
        #pragma unroll
        for (int c = 0; c < ADJ_CHUNKS - 1; ++c) {
            unsigned g = min(abase + (unsigned)(c * 1024), adjLim);
            gload_lds16((const char*)adj + g, buf + c * 1024);
        }
        if (lane < 45) {   // last 720 B
            unsigned g = min(abase + (unsigned)((ADJ_CHUNKS - 1) * 1024), adjLim);
            gload_lds16((const char*)adj + g, buf + (ADJ_CHUNKS - 1) * 1024);
        }
        // nf: 3 DMA ops
        unsigned nbase = (unsigned)t * NF_TILE_B + lane * 16;
        #pragma unroll
        for (int c = 0; c < 2; ++c) {
            unsigned g = min(nbase + (unsigned)(c * 1024), nfLim);
            gload_lds16((const char*)nf + g, buf + ADJ_TILE_B + c * 1024);
        }
        if (lane < 3) {    // last 40 B (rounded to 48, section padded)
            unsigned g = min(nbase + 2048u, nfLim);
            gload_lds16((const char*)nf + g, buf + ADJ_TILE_B + 2048);
        }
    };

    auto compute = [&](int t, const char* buf) {
        const int nb = min(TILE, B - t * TILE);
        if (lane >= nb) return;
        const int b = t * TILE + lane;
        const float pw = proj_w[0], pb = proj_b[0];
        const float* __restrict__ my = (const float*)buf + lane * ADJ_F;
        const float2* __restrict__ xp = (const float2*)(buf + ADJ_TILE_B + lane * NF_B);

        float x[NNODE];
        #pragma unroll
        for (int j = 0; j < 9; ++j) { float2 v = xp[j]; x[2*j] = v.x; x[2*j+1] = v.y; }

        // Layer 1: deg (row-sum) + matvec in one sweep.
        // h = relu( w*(A x)/deg + pb )  since A*1 = deg and proj is 1x1
        float invd[NNODE], h[NNODE];
        #pragma unroll
        for (int n = 0; n < NNODE; ++n) {
            const float2* __restrict__ row = (const float2*)(my + n * NNODE);
            float d = 0.f, s = 0.f;
            #pragma unroll
            for (int m = 0; m < 9; ++m) {
                float2 a = row[m];                 // ds_read_b64, ~4-way conflict (29 lanes)
                d += a.x + a.y;
                s += a.x * x[2*m] + a.y * x[2*m+1];
            }
            float inv = 1.0f / d;
            invd[n] = inv;
            h[n] = fmaxf(0.f, pw * s * inv + pb);
        }

        // Layer 2: rows re-read from resident LDS, reuse 1/deg
        float y[NNODE];
        #pragma unroll
        for (int n = 0; n < NNODE; ++n) {
            const float2* __restrict__ row = (const float2*)(my + n * NNODE);
            float s = 0.f;
            #pragma unroll
            for (int m = 0; m < 9; ++m) {
                float2 a = row[m];
                s += a.x * h[2*m] + a.y * h[2*m+1];
            }
            float v = fmaxf(0.f, pw * s * invd[n] + pb);
            y[n] = (v != v) ? 0.f : v;             // NaN scrub (matches reference)
        }

        // MLP head: lane-uniform weight loads (scalar/broadcast, loop-invariant hoisted)
        float z1[10];
        #pragma unroll
        for (int k = 0; k < 10; ++k) {
            float s = b1[k];
            #pragma unroll
            for (int j = 0; j < NNODE; ++j) s += w1[k*NNODE + j] * y[j];
            z1[k] = fmaxf(0.f, s);
        }
        float z2[8];
        #pragma unroll
        for (int k = 0; k < 8; ++k) {
            float s = b2[k];
            #pragma unroll
            for (int j = 0; j < 10; ++j) s += w2[k*10 + j] * z1[j];
            z2[k] = fmaxf(0.f, s);
        }
        float o0 = b3[0], o1 = b3[1];
        #pragma unroll
        for (int j = 0; j < 8; ++j) { o0 += w3[j] * z2[j]; o1 += w3[8 + j] * z2[j]; }

        *(float2*)(out + (size_t)b * 2) = make_float2(o0, o1);
    };

    // ---- Persistent double-buffered pipeline: the DMA stream never drains ----
    int t = blockIdx.x;                // GRID=512 <= NT always
    stage(t, bA);                      // prologue: 40 ops in flight
    for (; t < NT; t += GRID) {
        const int tn = t + GRID;
        if (tn < NT) {
            stage(tn, bB);             // +40 ops (newest)
            // wait until only the newest STAGE_OPS remain -> current buffer resident;
            // next tile's stream stays in flight under compute (T4: never vmcnt(0))
            asm volatile("s_waitcnt vmcnt(40)" ::: "memory");
        } else {
            asm volatile("s_waitcnt vmcnt(0)" ::: "memory");
        }
        compute(t, bA);
        char* tmp = bA; bA = bB; bB = tmp;
    }
}

extern "C" void kernel_launch(void* const* d_in, const int* in_sizes, int n_in,
                              void* d_out, int out_size, void* d_ws, size_t ws_size,
                              hipStream_t stream) {
    const float* nf  = (const float*)d_in[0];
    const float* adj = (const float*)d_in[1];
    const float* pw  = (const float*)d_in[2];
    const float* pb  = (const float*)d_in[3];
    const float* w1  = (const float*)d_in[4];
    const float* b1  = (const float*)d_in[5];
    const float* w2  = (const float*)d_in[6];
    const float* b2  = (const float*)d_in[7];
    const float* w3  = (const float*)d_in[8];
    const float* b3  = (const float*)d_in[9];
    float* out = (float*)d_out;

    const int B = in_sizes[0] / NNODE;              // 131072
    const size_t ldsBytes = 2 * BUF_B;              // 79,360 B -> 2 blocks/CU

    hipFuncSetAttribute(reinterpret_cast<const void*>(gcnn_fused),
                        hipFuncAttributeMaxDynamicSharedMemorySize, (int)ldsBytes);

    gcnn_fused<<<GRID, 64, ldsBytes, stream>>>(nf, adj, pw, pb, w1, b1, w2, b2, w3, b3, out, B);
}

// Round 5
// 45.951 us; speedup vs baseline: 1.5284x; 1.5284x over previous
//
#include <hip/hip_runtime.h>

#define NNODE  18
#define QBATCH 16                 // batches per wave: 4 lanes (a quad) per batch

// quad_perm broadcast of lane P within each 4-lane group (bit15=1 -> quad mode)
#define QB(v, P) __int_as_float(__builtin_amdgcn_ds_swizzle(__float_as_int(v), 0x8000 + 0x55 * (P)))
// gather full 18-vector from quad-distributed slots: element m lives in lane (m&3), slot (m>>2)
#define GATHER18(dst, src)                                                      \
    dst[0]=QB(src[0],0);  dst[1]=QB(src[0],1);  dst[2]=QB(src[0],2);  dst[3]=QB(src[0],3);   \
    dst[4]=QB(src[1],0);  dst[5]=QB(src[1],1);  dst[6]=QB(src[1],2);  dst[7]=QB(src[1],3);   \
    dst[8]=QB(src[2],0);  dst[9]=QB(src[2],1);  dst[10]=QB(src[2],2); dst[11]=QB(src[2],3);  \
    dst[12]=QB(src[3],0); dst[13]=QB(src[3],1); dst[14]=QB(src[3],2); dst[15]=QB(src[3],3);  \
    dst[16]=QB(src[4],0); dst[17]=QB(src[4],1);

__global__ __launch_bounds__(64, 3) void gcnn_fused(
    const float* __restrict__ nf,      // [B,18]
    const float* __restrict__ adj,     // [B,18,18]
    const float* __restrict__ proj_w, const float* __restrict__ proj_b,
    const float* __restrict__ w1, const float* __restrict__ b1,   // [10,18],[10]
    const float* __restrict__ w2, const float* __restrict__ b2,   // [8,10],[8]
    const float* __restrict__ w3, const float* __restrict__ b3,   // [2,8],[2]
    float* __restrict__ out,           // [B,2]
    int B)
{
    const int lane = threadIdx.x;      // block = 1 wave, no LDS, no barriers
    const int q    = lane >> 2;        // batch within tile (0..15)
    const int p    = lane & 3;         // quad lane: owns rows r ≡ p (mod 4)
    const int b    = blockIdx.x * QBATCH + q;
    if (b >= B) return;

    // ---- Load owned adj rows into REGISTERS (static indices; quad covers whole batch) ----
    // Lane p, slot t -> row r = 4t+p (slots 4 of lanes 2,3 are clamped dummies, unused).
    float a[5][NNODE];
    const char* abase = (const char*)adj + (size_t)b * 1296;
    #pragma unroll
    for (int t = 0; t < 5; ++t) {
        int r  = 4 * t + p;
        int ro = r < NNODE ? r : NNODE - 1;               // clamp: keeps tail lanes in-bounds
        const float2* __restrict__ rp = (const float2*)(abase + ro * 72);
        #pragma unroll
        for (int j = 0; j < 9; ++j) { float2 v = rp[j]; a[t][2*j] = v.x; a[t][2*j+1] = v.y; }
    }

    // ---- x: 18 floats, same address across the quad (broadcast-friendly, L1-served) ----
    float x[NNODE];
    const float2* __restrict__ xp = (const float2*)(nf + (size_t)b * NNODE);
    #pragma unroll
    for (int j = 0; j < 9; ++j) { float2 v = xp[j]; x[2*j] = v.x; x[2*j+1] = v.y; }

    const float pw = proj_w[0], pb = proj_b[0];

    // ---- Layer 1: per-slot row-sum (deg) + dot; h = relu(pw*(A x)/deg + pb)  (A·1 = deg) ----
    float inv[5], h[5];
    #pragma unroll
    for (int t = 0; t < 5; ++t) {
        float d = 0.f, s = 0.f;
        #pragma unroll
        for (int m = 0; m < NNODE; ++m) { d += a[t][m]; s += a[t][m] * x[m]; }
        inv[t] = 1.0f / d;
        h[t]   = fmaxf(0.f, pw * s * inv[t] + pb);
    }

    // ---- Broadcast h across the quad (register permute, no LDS storage) ----
    float hf[NNODE];
    GATHER18(hf, h)

    // ---- Layer 2 from register-resident A; NaN-scrub per reference ----
    float y[5];
    #pragma unroll
    for (int t = 0; t < 5; ++t) {
        float s = 0.f;
        #pragma unroll
        for (int m = 0; m < NNODE; ++m) s += a[t][m] * hf[m];
        float v = fmaxf(0.f, pw * s * inv[t] + pb);
        y[t] = (v != v) ? 0.f : v;
    }

    float yf[NNODE];
    GATHER18(yf, y)

    // ---- MLP head (quad-redundant; weights are lane-uniform -> scalar loads) ----
    float z1[10];
    #pragma unroll
    for (int k = 0; k < 10; ++k) {
        float s = b1[k];
        #pragma unroll
        for (int j = 0; j < NNODE; ++j) s += w1[k*NNODE + j] * yf[j];
        z1[k] = fmaxf(0.f, s);
    }
    float z2[8];
    #pragma unroll
    for (int k = 0; k < 8; ++k) {
        float s = b2[k];
        #pragma unroll
        for (int j = 0; j < 10; ++j) s += w2[k*10 + j] * z1[j];
        z2[k] = fmaxf(0.f, s);
    }
    float o0 = b3[0], o1 = b3[1];
    #pragma unroll
    for (int j = 0; j < 8; ++j) { o0 += w3[j] * z2[j]; o1 += w3[8 + j] * z2[j]; }

    if (p == 0)
        *(float2*)(out + (size_t)b * 2) = make_float2(o0, o1);   // 16 stores/wave, contiguous
}

extern "C" void kernel_launch(void* const* d_in, const int* in_sizes, int n_in,
                              void* d_out, int out_size, void* d_ws, size_t ws_size,
                              hipStream_t stream) {
    const float* nf  = (const float*)d_in[0];
    const float* adj = (const float*)d_in[1];
    const float* pw  = (const float*)d_in[2];
    const float* pb  = (const float*)d_in[3];
    const float* w1  = (const float*)d_in[4];
    const float* b1  = (const float*)d_in[5];
    const float* w2  = (const float*)d_in[6];
    const float* b2  = (const float*)d_in[7];
    const float* w3  = (const float*)d_in[8];
    const float* b3  = (const float*)d_in[9];
    float* out = (float*)d_out;

    const int B = in_sizes[0] / NNODE;                    // 131072
    const int grid = (B + QBATCH - 1) / QBATCH;           // 8192 one-wave blocks

    gcnn_fused<<<grid, 64, 0, stream>>>(nf, adj, pw, pb, w1, b1, w2, b2, w3, b3, out, B);
}

// Round 6
// 35.794 us; speedup vs baseline: 1.9621x; 1.2837x over previous
//
#include <hip/hip_runtime.h>

#define NNODE  18
#define ADJ_B  1296                      // bytes per batch matrix
#define ADJ_F  324                       // floats per batch matrix
#define TILE   40                        // batches per block
#define TILE_BYTES (TILE * ADJ_B)        // 51,840 B LDS -> 3 blocks/CU (155,520 <= 163,840)
#define ROUNDS 13                        // ceil(51840 / 4096)

// Direct global->LDS DMA: per-lane global src, WAVE-UNIFORM LDS base (+lane*16 in HW).
__device__ __forceinline__ void gload_lds16(const void* g, void* l) {
    __builtin_amdgcn_global_load_lds((const __attribute__((address_space(1))) void*)g,
                                     (__attribute__((address_space(3))) void*)l, 16, 0, 0);
}

// quad_perm broadcast of lane P within each 4-lane group (bit15=1 -> quad mode)
#define QB(v, P) __int_as_float(__builtin_amdgcn_ds_swizzle(__float_as_int(v), 0x8000 + 0x55 * (P)))
#define GATHER18(dst, src)                                                      \
    dst[0]=QB(src[0],0);  dst[1]=QB(src[0],1);  dst[2]=QB(src[0],2);  dst[3]=QB(src[0],3);   \
    dst[4]=QB(src[1],0);  dst[5]=QB(src[1],1);  dst[6]=QB(src[1],2);  dst[7]=QB(src[1],3);   \
    dst[8]=QB(src[2],0);  dst[9]=QB(src[2],1);  dst[10]=QB(src[2],2); dst[11]=QB(src[2],3);  \
    dst[12]=QB(src[3],0); dst[13]=QB(src[3],1); dst[14]=QB(src[3],2); dst[15]=QB(src[3],3);  \
    dst[16]=QB(src[4],0); dst[17]=QB(src[4],1);

__global__ __launch_bounds__(256, 3) void gcnn_fused(
    const float* __restrict__ nf,      // [B,18]
    const float* __restrict__ adj,     // [B,18,18]
    const float* __restrict__ proj_w, const float* __restrict__ proj_b,
    const float* __restrict__ w1, const float* __restrict__ b1,   // [10,18],[10]
    const float* __restrict__ w2, const float* __restrict__ b2,   // [8,10],[8]
    const float* __restrict__ w3, const float* __restrict__ b3,   // [2,8],[2]
    float* __restrict__ out,           // [B,2]
    int B)
{
    extern __shared__ __align__(16) char smem[];   // TILE_BYTES, LINEAR (DMA dest)
    const int tid  = threadIdx.x;                  // 256 threads = 4 waves
    const int wave = tid >> 6;
    const int lane = tid & 63;
    const int p    = tid & 3;                      // quad lane: owns rows r ≡ p (mod 4)
    const int Q    = tid >> 2;                     // quad index = batch within tile (0..63)
    const int b0   = blockIdx.x * TILE;
    const int nb   = min(TILE, B - b0);
    const int nbytes = nb * ADJ_B;
    const int b    = b0 + Q;

    // ---- x loads first: quad-uniform addresses; latency hides under the DMA drain ----
    float x[NNODE];
    if (Q < nb) {
        const float2* __restrict__ xp = (const float2*)(nf + (size_t)b * NNODE);
        #pragma unroll
        for (int j = 0; j < 9; ++j) { float2 v = xp[j]; x[2*j] = v.x; x[2*j+1] = v.y; }
    }

    // ---- Stage adj tile: fully-coalesced DMA (min segment lookups), linear LDS ----
    const char* __restrict__ gbase = (const char*)adj + (size_t)b0 * ADJ_B;
    #pragma unroll
    for (int r = 0; r < ROUNDS; ++r) {
        const int ow  = r * 4096 + wave * 1024;    // wave-uniform LDS base
        const int off = ow + lane * 16;
        if (off < nbytes) gload_lds16(gbase + off, smem + ow);
    }
    __syncthreads();   // vmcnt(0)+barrier: tile resident (other 2 CU-resident blocks cover)

    if (Q < nb) {
        // ---- LDS -> registers: lane p reads rows 4t+p of its quad's batch ----
        float a[5][NNODE];
        const float* __restrict__ my = (const float*)smem + Q * ADJ_F;
        #pragma unroll
        for (int t = 0; t < 5; ++t) {
            int r  = 4 * t + p;
            int ro = r < NNODE ? r : NNODE - 1;    // lanes p>=2,t=4: clamped dummy (unused)
            const float2* __restrict__ rp = (const float2*)(my + ro * NNODE);
            #pragma unroll
            for (int j = 0; j < 9; ++j) { float2 v = rp[j]; a[t][2*j] = v.x; a[t][2*j+1] = v.y; }
        }

        const float pw = proj_w[0], pb = proj_b[0];

        // ---- Layer 1: h = relu(pw*(A x)/deg + pb), deg = row-sum (A·1 = deg) ----
        float inv[5], h[5];
        #pragma unroll
        for (int t = 0; t < 5; ++t) {
            float d = 0.f, s = 0.f;
            #pragma unroll
            for (int m = 0; m < NNODE; ++m) { d += a[t][m]; s += a[t][m] * x[m]; }
            inv[t] = 1.0f / d;
            h[t]   = fmaxf(0.f, pw * s * inv[t] + pb);
        }

        // ---- Broadcast h across the quad (register permutes, no LDS traffic) ----
        float hf[NNODE];
        GATHER18(hf, h)

        // ---- Layer 2 from register-resident A; NaN-scrub per reference ----
        float y[5];
        #pragma unroll
        for (int t = 0; t < 5; ++t) {
            float s = 0.f;
            #pragma unroll
            for (int m = 0; m < NNODE; ++m) s += a[t][m] * hf[m];
            float v = fmaxf(0.f, pw * s * inv[t] + pb);
            y[t] = (v != v) ? 0.f : v;
        }

        float yf[NNODE];
        GATHER18(yf, y)

        // ---- MLP head (quad-redundant; weights lane-uniform -> scalar loads) ----
        float z1[10];
        #pragma unroll
        for (int k = 0; k < 10; ++k) {
            float s = b1[k];
            #pragma unroll
            for (int j = 0; j < NNODE; ++j) s += w1[k*NNODE + j] * yf[j];
            z1[k] = fmaxf(0.f, s);
        }
        float z2[8];
        #pragma unroll
        for (int k = 0; k < 8; ++k) {
            float s = b2[k];
            #pragma unroll
            for (int j = 0; j < 10; ++j) s += w2[k*10 + j] * z1[j];
            z2[k] = fmaxf(0.f, s);
        }
        float o0 = b3[0], o1 = b3[1];
        #pragma unroll
        for (int j = 0; j < 8; ++j) { o0 += w3[j] * z2[j]; o1 += w3[8 + j] * z2[j]; }

        if (p == 0)
            *(float2*)(out + (size_t)b * 2) = make_float2(o0, o1);
    }
}

extern "C" void kernel_launch(void* const* d_in, const int* in_sizes, int n_in,
                              void* d_out, int out_size, void* d_ws, size_t ws_size,
                              hipStream_t stream) {
    const float* nf  = (const float*)d_in[0];
    const float* adj = (const float*)d_in[1];
    const float* pw  = (const float*)d_in[2];
    const float* pb  = (const float*)d_in[3];
    const float* w1  = (const float*)d_in[4];
    const float* b1  = (const float*)d_in[5];
    const float* w2  = (const float*)d_in[6];
    const float* b2  = (const float*)d_in[7];
    const float* w3  = (const float*)d_in[8];
    const float* b3  = (const float*)d_in[9];
    float* out = (float*)d_out;

    const int B = in_sizes[0] / NNODE;                    // 131072
    const int grid = (B + TILE - 1) / TILE;               // 3277 blocks

    hipFuncSetAttribute(reinterpret_cast<const void*>(gcnn_fused),
                        hipFuncAttributeMaxDynamicSharedMemorySize, TILE_BYTES);

    gcnn_fused<<<grid, 256, TILE_BYTES, stream>>>(nf, adj, pw, pb, w1, b1, w2, b2, w3, b3, out, B);
}